// Round 19
// baseline (627.313 us; speedup 1.0000x reference)
//
#include <hip/hip_runtime.h>
#include <hip/hip_bf16.h>

// B=64, T=2048, D=784, N1=100, N2=10, dt=0.04
// Pipeline (r16 base + fused_scan experiment):
//   prep_w16 : W1 -> fp16 2-way split (h, r*1024) fragment-order image (r16 verbatim)
//   gemm1_w  : barrier-free persistent-W GEMM (r16 verbatim, 2-deep A flight)
//   fused_scan5: r16's fused_scan3 with 8-deep z ring buffer (bit-exact) and
//              x5 IDEMPOTENT repetition (diagnostic: surfaces in rocprof top-5;
//              dur/5 vs 58us scores the prefetch theory)
//
// ws: Wg 358400 B | z1p 131072*100 f32 (52.4 MB)

#define FHN_DT 0.04f

typedef _Float16 f16x8 __attribute__((ext_vector_type(8)));
typedef __attribute__((ext_vector_type(4))) float f32x4;

__device__ __forceinline__ void gl16(const void* g, void* l) {
    __builtin_amdgcn_global_load_lds(
        (const __attribute__((address_space(1))) unsigned int*)g,
        (__attribute__((address_space(3))) unsigned int*)l, 16, 0, 0);
}

__device__ __forceinline__ void sync_lds() {
    asm volatile("s_waitcnt lgkmcnt(0)" ::: "memory");
    __builtin_amdgcn_s_barrier();
    asm volatile("" ::: "memory");
}

// ---------------- prep: W1 (100x784) -> fragment-order fp16 split image (r16 verbatim) ----------------
__global__ void prep_w16(const float* __restrict__ W1, unsigned short* __restrict__ Wg) {
    int idx = blockIdx.x * 256 + threadIdx.x;
    if (idx >= 179200) return;
    int kt   = idx / 7168;
    int rem  = idx % 7168;
    int f    = rem >> 9;
    int r2   = rem & 511;
    int l    = r2 >> 3;
    int e    = r2 & 7;
    int term = f / 7, ct = f % 7;
    int n = ct * 16 + (l & 15);
    int k = kt * 32 + (l >> 4) * 8 + e;
    float v = (n < 100 && k < 784) ? W1[n * 784 + k] : 0.0f;
    _Float16 h = (_Float16)v;
    unsigned short o;
    if (term == 0) o = __builtin_bit_cast(unsigned short, h);
    else           o = __builtin_bit_cast(unsigned short, (_Float16)((v - (float)h) * 1024.0f));
    Wg[idx] = o;
}

// ---------------- GEMM1: barrier-free K-loop, W persistent in LDS (r16 verbatim) ----------------
__global__ __launch_bounds__(512, 1) void gemm1_w(const float* __restrict__ A,
                                                  const unsigned short* __restrict__ Wg,
                                                  float* __restrict__ z1p) {
    __shared__ __align__(16) char smem[129024];    // 9 tiles x 14336 B (max section)
    const int tid  = threadIdx.x;                  // 0..511
    const int w    = tid >> 6;                     // 0..7
    const int lane = tid & 63;
    const int ln   = lane & 15;
    const int kg   = lane >> 4;                    // k-slice = kg*8
    const long row0 = (long)blockIdx.x * 256;

    const float* arow0 = A + (row0 + w * 32 + ln) * 784 + kg * 8;
    const float* arow1 = arow0 + (size_t)16 * 784;

    f32x4 acc1[2][7] = {};
    f32x4 acc2[2][7] = {};
    float afpA[16], afpB[16];      // [0..7] row0, [8..15] row1

#define ISSUE_A(T, AF) {                                                        \
        if ((T) == 24 && kg >= 2) {                                             \
            *(float4*)&AF[0]  = make_float4(0.f, 0.f, 0.f, 0.f);                \
            *(float4*)&AF[4]  = make_float4(0.f, 0.f, 0.f, 0.f);                \
            *(float4*)&AF[8]  = make_float4(0.f, 0.f, 0.f, 0.f);                \
            *(float4*)&AF[12] = make_float4(0.f, 0.f, 0.f, 0.f);                \
        } else {                                                                \
            *(float4*)&AF[0]  = *(const float4*)(arow0 + (T) * 32);             \
            *(float4*)&AF[4]  = *(const float4*)(arow0 + (T) * 32 + 4);         \
            *(float4*)&AF[8]  = *(const float4*)(arow1 + (T) * 32);             \
            *(float4*)&AF[12] = *(const float4*)(arow1 + (T) * 32 + 4);         \
        } }

#define LOADSEC(TS, NB) {                                                       \
        const char* src_ = (const char*)Wg + (size_t)(TS) * 14336;              \
        _Pragma("unroll 1")                                                     \
        for (int c_ = 0; c_ < (NB) / 8192; ++c_)                                \
            gl16(src_ + c_ * 8192 + tid * 16, smem + c_ * 8192 + tid * 16);     \
        if (((NB) & 8191) != 0 && tid * 16 < ((NB) & 8191))                     \
            gl16(src_ + ((NB) / 8192) * 8192 + tid * 16,                        \
                 smem + ((NB) / 8192) * 8192 + tid * 16);                       \
    }

#define SEC_SYNC() {                                                            \
        asm volatile("s_waitcnt vmcnt(0)" ::: "memory");                        \
        __builtin_amdgcn_s_barrier();                                           \
        asm volatile("" ::: "memory");                                          \
    }

#define BODY(KT, AF, TS) {                                                      \
        f16x8 ah0, al0, ah1, al1;                                               \
        _Pragma("unroll")                                                       \
        for (int e_ = 0; e_ < 8; ++e_) {                                        \
            float a0_ = AF[e_], a1_ = AF[8 + e_];                               \
            _Float16 h0_ = (_Float16)a0_, h1_ = (_Float16)a1_;                  \
            ah0[e_] = h0_; ah1[e_] = h1_;                                       \
            al0[e_] = (_Float16)((a0_ - (float)h0_) * 1024.0f);                 \
            al1[e_] = (_Float16)((a1_ - (float)h1_) * 1024.0f);                 \
        }                                                                       \
        if ((KT) < 23) ISSUE_A((KT) + 2, AF);                                   \
        const char* cb_ = smem + ((KT) - (TS)) * 14336 + lane * 16;             \
        _Pragma("unroll")                                                       \
        for (int ct_ = 0; ct_ < 7; ++ct_) {                                     \
            f16x8 bh = *(const f16x8*)(cb_ + ct_ * 1024);                       \
            f16x8 bl = *(const f16x8*)(cb_ + 7168 + ct_ * 1024);                \
            acc1[0][ct_] = __builtin_amdgcn_mfma_f32_16x16x32_f16(ah0, bh, acc1[0][ct_], 0, 0, 0); \
            acc2[0][ct_] = __builtin_amdgcn_mfma_f32_16x16x32_f16(ah0, bl, acc2[0][ct_], 0, 0, 0); \
            acc2[0][ct_] = __builtin_amdgcn_mfma_f32_16x16x32_f16(al0, bh, acc2[0][ct_], 0, 0, 0); \
            acc1[1][ct_] = __builtin_amdgcn_mfma_f32_16x16x32_f16(ah1, bh, acc1[1][ct_], 0, 0, 0); \
            acc2[1][ct_] = __builtin_amdgcn_mfma_f32_16x16x32_f16(ah1, bl, acc2[1][ct_], 0, 0, 0); \
            acc2[1][ct_] = __builtin_amdgcn_mfma_f32_16x16x32_f16(al1, bh, acc2[1][ct_], 0, 0, 0); \
        } }

    ISSUE_A(0, afpA);
    ISSUE_A(1, afpB);

    // ---- section 0: tiles 0..8 ----
    LOADSEC(0, 129024);
    SEC_SYNC();
#pragma unroll 1
    for (int k0 = 0; k0 < 8; k0 += 2) { BODY(k0, afpA, 0); BODY(k0 + 1, afpB, 0); }
    BODY(8, afpA, 0);

    // ---- section 1: tiles 9..16 ----
    asm volatile("" ::: "memory");
    __builtin_amdgcn_s_barrier();
    asm volatile("" ::: "memory");
    LOADSEC(9, 114688);
    SEC_SYNC();
#pragma unroll 1
    for (int k0 = 9; k0 < 17; k0 += 2) { BODY(k0, afpB, 9); BODY(k0 + 1, afpA, 9); }

    // ---- section 2: tiles 17..24 ----
    asm volatile("" ::: "memory");
    __builtin_amdgcn_s_barrier();
    asm volatile("" ::: "memory");
    LOADSEC(17, 114688);
    SEC_SYNC();
#pragma unroll 1
    for (int k0 = 17; k0 < 25; k0 += 2) { BODY(k0, afpB, 17); BODY(k0 + 1, afpA, 17); }

#pragma unroll
    for (int ct = 0; ct < 7; ++ct) {
        int n = ct * 16 + ln;
        if (n < 100) {
#pragma unroll
            for (int rt = 0; rt < 2; ++rt) {
                long rg = row0 + w * 32 + rt * 16 + kg * 4;
                float* p = z1p + rg * 100 + n;
#pragma unroll
                for (int r = 0; r < 4; ++r)
                    p[r * 100] = fmaf(acc2[rt][ct][r], 0.0009765625f, acc1[rt][ct][r]);
            }
        }
    }
#undef ISSUE_A
#undef LOADSEC
#undef SEC_SYNC
#undef BODY
}

// ---------------- fused_scan5: r16 fused_scan3 + 8-deep z ring + x5 idempotent reps ----------------
// 64 blocks x 576. tid 0..99 scan1; 128..511 gemm2+copyout; 512..521 scan2.
// scan1: 8 static ring buffers; consume zbuf[g%8], then refill with group g+8
// (issue right after consumption -> ~7 groups of compute cover). Bit-exact loads.
__global__ __launch_bounds__(576) void fused_scan5(const float* __restrict__ z1p,
                                                   const float* __restrict__ W2,
                                                   float* __restrict__ out) {
    __shared__ float fsm[32768];
    const int tid = threadIdx.x;
    const int b   = blockIdx.x;
    const float dt = FHN_DT;

    const float* zb = z1p + (long)b * 2048 * 100 + tid;   // scan1 lanes only
    float zr0[16], zr1[16], zr2[16], zr3[16], zr4[16], zr5[16], zr6[16], zr7[16];

    const int tg = tid - 128;                             // gemm2 threads: 0..383
    int pp = (tg >> 7) & 3;
    pp = __builtin_amdgcn_readfirstlane(pp);
    const int r  = tg & 127;
    const int mb = (pp == 0) ? 0 : (pp == 1 ? 4 : 7);
    const int mc = (pp == 0) ? 4 : 3;
    const int m2 = tid - 512;                             // scan2 lane id 0..9

#pragma unroll 1
    for (int rep = 0; rep < 5; ++rep) {
        float V = 0.f, S = 0.f;
        if (tid < 100) {
#define LD8(ZC, G) { _Pragma("unroll") for (int u = 0; u < 16; ++u) ZC[u] = zb[((G) * 16 + u) * 100]; }
            LD8(zr0, 0) LD8(zr1, 1) LD8(zr2, 2) LD8(zr3, 3)
            LD8(zr4, 4) LD8(zr5, 5) LD8(zr6, 6) LD8(zr7, 7)
#undef LD8
        }

        for (int i = 0; i <= 18; ++i) {
            if (tid < 128) {
                bool a1 = (tid < 100) && (i < 16);
                if (a1) {
                    const int cw = i & 1;
#define S1STEP(SUB, ZC) {                                                       \
                    _Pragma("unroll")                                           \
                    for (int u = 0; u < 16; ++u) {                              \
                        int tl = (SUB) * 16 + u;                                \
                        fsm[cw * 14848 + tl * 116 + tid] = V;                   \
                        float z  = ZC[u];                                       \
                        float V3 = V * V * V;                                   \
                        float Vn = fmaf(1.f + dt, V,                            \
                                    fmaf(-dt / 3.f, V3, fmaf(-dt, S, dt * z))); \
                        float Sn = fmaf(dt * 0.08f, V + 0.7f - 0.8f * S, S);    \
                        V = Vn; S = Sn;                                         \
                    }                                                           \
                    {                                                           \
                        int tn = (i * 8 + (SUB) + 8) * 16;                      \
                        if (tn < 2048) {                                        \
                            _Pragma("unroll")                                   \
                            for (int u = 0; u < 16; ++u)                        \
                                ZC[u] = zb[(tn + u) * 100];                     \
                        }                                                       \
                    } }
                    S1STEP(0, zr0) S1STEP(1, zr1) S1STEP(2, zr2) S1STEP(3, zr3)
                    S1STEP(4, zr4) S1STEP(5, zr5) S1STEP(6, zr6) S1STEP(7, zr7)
#undef S1STEP
                }
            } else if (tid < 512) {
                if (i >= 1 && i <= 16) {
                    const int pb = (i - 1) & 1;
                    float acc[4] = {0.f, 0.f, 0.f, 0.f};
                    for (int kq = 0; kq < 25; ++kq) {
                        float4 v = *(const float4*)&fsm[pb * 14848 + r * 116 + kq * 4];
#pragma unroll
                        for (int j = 0; j < 4; ++j) {
                            if (j < mc) {
                                const float* wp = W2 + (mb + j) * 100 + kq * 4;  // uniform -> s_load
                                acc[j] = fmaf(v.x, wp[0], acc[j]);
                                acc[j] = fmaf(v.y, wp[1], acc[j]);
                                acc[j] = fmaf(v.z, wp[2], acc[j]);
                                acc[j] = fmaf(v.w, wp[3], acc[j]);
                            }
                        }
                    }
#pragma unroll
                    for (int j = 0; j < 4; ++j)
                        if (j < mc) fsm[29696 + pb * 1536 + r * 12 + mb + j] = 0.5f * acc[j];
                }
                if (i >= 3) {
                    const int pb = (i - 1) & 1;
                    float* dst = out + ((long)b * 2048 + (long)(i - 3) * 128 + r) * 10;
#pragma unroll
                    for (int j = 0; j < 4; ++j)
                        if (j < mc) dst[mb + j] = fsm[pb * 14848 + r * 116 + 100 + mb + j];
                }
            } else {
                bool a2 = (m2 < 10) && (i >= 2) && (i < 18);
                if (a2) {
                    const int cw = i & 1;
#pragma unroll
                    for (int sub = 0; sub < 8; ++sub) {
                        float z0s[16];
#pragma unroll
                        for (int u = 0; u < 16; ++u)
                            z0s[u] = fsm[29696 + cw * 1536 + (sub * 16 + u) * 12 + m2];
#pragma unroll
                        for (int u = 0; u < 16; ++u) {
                            int tl = sub * 16 + u;
                            fsm[cw * 14848 + tl * 116 + 100 + m2] = V;
                            float z  = z0s[u];
                            float V3 = V * V * V;
                            float Vn = fmaf(1.f + dt, V,
                                        fmaf(-dt / 3.f, V3, fmaf(-dt, S, dt * z)));
                            float Sn = fmaf(dt * 0.08f, V + 0.7f - 0.8f * S, S);
                            V = Vn; S = Sn;
                        }
                    }
                }
            }
            sync_lds();
        }
    }
}

extern "C" void kernel_launch(void* const* d_in, const int* in_sizes, int n_in,
                              void* d_out, int out_size, void* d_ws, size_t ws_size,
                              hipStream_t stream) {
    const float* batch = (const float*)d_in[0];   // 64*2048*784
    const float* W1    = (const float*)d_in[1];   // 100*784
    const float* W2    = (const float*)d_in[2];   // 10*100
    float* out = (float*)d_out;                   // 64*2048*10

    char* base = (char*)d_ws;
    unsigned short* Wg = (unsigned short*)base;   // 358400 B
    float* z1p = (float*)(base + 358400);         // 131072*100 f32

    prep_w16<<<700, 256, 0, stream>>>(W1, Wg);
    gemm1_w<<<512, 512, 0, stream>>>(batch, Wg, z1p);
    fused_scan5<<<64, 576, 0, stream>>>(z1p, W2, out);
}

// Round 20
// 196.166 us; speedup vs baseline: 3.1979x; 3.1979x over previous
//
#include <hip/hip_runtime.h>
#include <hip/hip_bf16.h>

// B=64, T=2048, D=784, N1=100, N2=10, dt=0.04
// Pipeline:
//   prep_w16 : W1 -> fp16 2-way split fragment-order image (r16 verbatim)
//   gemm1_w  : barrier-free persistent-W GEMM (r16 verbatim) — measured ~70us,
//              at the HBM floor.
//   fused_scan6: scan1+gemm2+scan2 with z STAGED INTO LDS by the gemm2 waves
//              via global_load_lds (double-buffered, chunk=64 steps). scan1
//              reads z from LDS (no global loads on scan waves at all).
//              Fixes r19's finding: scan phase was z-read-BW-starved (110us).
//
// ws: Wg 358400 B | z1p 131072*100 f32 (52.4 MB)

#define FHN_DT 0.04f

typedef _Float16 f16x8 __attribute__((ext_vector_type(8)));
typedef __attribute__((ext_vector_type(4))) float f32x4;

__device__ __forceinline__ void gl16(const void* g, void* l) {
    __builtin_amdgcn_global_load_lds(
        (const __attribute__((address_space(1))) unsigned int*)g,
        (__attribute__((address_space(3))) unsigned int*)l, 16, 0, 0);
}

__device__ __forceinline__ void sync_lds() {
    asm volatile("s_waitcnt lgkmcnt(0)" ::: "memory");
    __builtin_amdgcn_s_barrier();
    asm volatile("" ::: "memory");
}

// ---------------- prep: W1 -> fragment-order fp16 split image (r16 verbatim) ----------------
__global__ void prep_w16(const float* __restrict__ W1, unsigned short* __restrict__ Wg) {
    int idx = blockIdx.x * 256 + threadIdx.x;
    if (idx >= 179200) return;
    int kt   = idx / 7168;
    int rem  = idx % 7168;
    int f    = rem >> 9;
    int r2   = rem & 511;
    int l    = r2 >> 3;
    int e    = r2 & 7;
    int term = f / 7, ct = f % 7;
    int n = ct * 16 + (l & 15);
    int k = kt * 32 + (l >> 4) * 8 + e;
    float v = (n < 100 && k < 784) ? W1[n * 784 + k] : 0.0f;
    _Float16 h = (_Float16)v;
    unsigned short o;
    if (term == 0) o = __builtin_bit_cast(unsigned short, h);
    else           o = __builtin_bit_cast(unsigned short, (_Float16)((v - (float)h) * 1024.0f));
    Wg[idx] = o;
}

// ---------------- GEMM1: barrier-free K-loop, W persistent in LDS (r16 verbatim) ----------------
__global__ __launch_bounds__(512, 1) void gemm1_w(const float* __restrict__ A,
                                                  const unsigned short* __restrict__ Wg,
                                                  float* __restrict__ z1p) {
    __shared__ __align__(16) char smem[129024];
    const int tid  = threadIdx.x;
    const int w    = tid >> 6;
    const int lane = tid & 63;
    const int ln   = lane & 15;
    const int kg   = lane >> 4;
    const long row0 = (long)blockIdx.x * 256;

    const float* arow0 = A + (row0 + w * 32 + ln) * 784 + kg * 8;
    const float* arow1 = arow0 + (size_t)16 * 784;

    f32x4 acc1[2][7] = {};
    f32x4 acc2[2][7] = {};
    float afpA[16], afpB[16];

#define ISSUE_A(T, AF) {                                                        \
        if ((T) == 24 && kg >= 2) {                                             \
            *(float4*)&AF[0]  = make_float4(0.f, 0.f, 0.f, 0.f);                \
            *(float4*)&AF[4]  = make_float4(0.f, 0.f, 0.f, 0.f);                \
            *(float4*)&AF[8]  = make_float4(0.f, 0.f, 0.f, 0.f);                \
            *(float4*)&AF[12] = make_float4(0.f, 0.f, 0.f, 0.f);                \
        } else {                                                                \
            *(float4*)&AF[0]  = *(const float4*)(arow0 + (T) * 32);             \
            *(float4*)&AF[4]  = *(const float4*)(arow0 + (T) * 32 + 4);         \
            *(float4*)&AF[8]  = *(const float4*)(arow1 + (T) * 32);             \
            *(float4*)&AF[12] = *(const float4*)(arow1 + (T) * 32 + 4);         \
        } }

#define LOADSEC(TS, NB) {                                                       \
        const char* src_ = (const char*)Wg + (size_t)(TS) * 14336;              \
        _Pragma("unroll 1")                                                     \
        for (int c_ = 0; c_ < (NB) / 8192; ++c_)                                \
            gl16(src_ + c_ * 8192 + tid * 16, smem + c_ * 8192 + tid * 16);     \
        if (((NB) & 8191) != 0 && tid * 16 < ((NB) & 8191))                     \
            gl16(src_ + ((NB) / 8192) * 8192 + tid * 16,                        \
                 smem + ((NB) / 8192) * 8192 + tid * 16);                       \
    }

#define SEC_SYNC() {                                                            \
        asm volatile("s_waitcnt vmcnt(0)" ::: "memory");                        \
        __builtin_amdgcn_s_barrier();                                           \
        asm volatile("" ::: "memory");                                          \
    }

#define BODY(KT, AF, TS) {                                                      \
        f16x8 ah0, al0, ah1, al1;                                               \
        _Pragma("unroll")                                                       \
        for (int e_ = 0; e_ < 8; ++e_) {                                        \
            float a0_ = AF[e_], a1_ = AF[8 + e_];                               \
            _Float16 h0_ = (_Float16)a0_, h1_ = (_Float16)a1_;                  \
            ah0[e_] = h0_; ah1[e_] = h1_;                                       \
            al0[e_] = (_Float16)((a0_ - (float)h0_) * 1024.0f);                 \
            al1[e_] = (_Float16)((a1_ - (float)h1_) * 1024.0f);                 \
        }                                                                       \
        if ((KT) < 23) ISSUE_A((KT) + 2, AF);                                   \
        const char* cb_ = smem + ((KT) - (TS)) * 14336 + lane * 16;             \
        _Pragma("unroll")                                                       \
        for (int ct_ = 0; ct_ < 7; ++ct_) {                                     \
            f16x8 bh = *(const f16x8*)(cb_ + ct_ * 1024);                       \
            f16x8 bl = *(const f16x8*)(cb_ + 7168 + ct_ * 1024);                \
            acc1[0][ct_] = __builtin_amdgcn_mfma_f32_16x16x32_f16(ah0, bh, acc1[0][ct_], 0, 0, 0); \
            acc2[0][ct_] = __builtin_amdgcn_mfma_f32_16x16x32_f16(ah0, bl, acc2[0][ct_], 0, 0, 0); \
            acc2[0][ct_] = __builtin_amdgcn_mfma_f32_16x16x32_f16(al0, bh, acc2[0][ct_], 0, 0, 0); \
            acc1[1][ct_] = __builtin_amdgcn_mfma_f32_16x16x32_f16(ah1, bh, acc1[1][ct_], 0, 0, 0); \
            acc2[1][ct_] = __builtin_amdgcn_mfma_f32_16x16x32_f16(ah1, bl, acc2[1][ct_], 0, 0, 0); \
            acc2[1][ct_] = __builtin_amdgcn_mfma_f32_16x16x32_f16(al1, bh, acc2[1][ct_], 0, 0, 0); \
        } }

    ISSUE_A(0, afpA);
    ISSUE_A(1, afpB);

    LOADSEC(0, 129024);
    SEC_SYNC();
#pragma unroll 1
    for (int k0 = 0; k0 < 8; k0 += 2) { BODY(k0, afpA, 0); BODY(k0 + 1, afpB, 0); }
    BODY(8, afpA, 0);

    asm volatile("" ::: "memory");
    __builtin_amdgcn_s_barrier();
    asm volatile("" ::: "memory");
    LOADSEC(9, 114688);
    SEC_SYNC();
#pragma unroll 1
    for (int k0 = 9; k0 < 17; k0 += 2) { BODY(k0, afpB, 9); BODY(k0 + 1, afpA, 9); }

    asm volatile("" ::: "memory");
    __builtin_amdgcn_s_barrier();
    asm volatile("" ::: "memory");
    LOADSEC(17, 114688);
    SEC_SYNC();
#pragma unroll 1
    for (int k0 = 17; k0 < 25; k0 += 2) { BODY(k0, afpB, 17); BODY(k0 + 1, afpA, 17); }

#pragma unroll
    for (int ct = 0; ct < 7; ++ct) {
        int n = ct * 16 + ln;
        if (n < 100) {
#pragma unroll
            for (int rt = 0; rt < 2; ++rt) {
                long rg = row0 + w * 32 + rt * 16 + kg * 4;
                float* p = z1p + rg * 100 + n;
#pragma unroll
                for (int r = 0; r < 4; ++r)
                    p[r * 100] = fmaf(acc2[rt][ct][r], 0.0009765625f, acc1[rt][ct][r]);
            }
        }
    }
#undef ISSUE_A
#undef LOADSEC
#undef SEC_SYNC
#undef BODY
}

// ---------------- fused_scan6: LDS-staged z, chunk=64 ----------------
// 64 blocks x 576 threads; chunks c=0..31 of 64 timesteps; iterations i=0..34:
//   waves 0-1 (tid<128, 100 active): scan1 chunk i   — z from LDS zst[i&1]
//   waves 2-7 (tid 128-511): DMA-stage z chunk i+1 -> zst[(i+1)&1] (gl16),
//                            gemm2 chunk i-1, copy-out chunk i-3; vmcnt(0) at end
//   wave 8   (tid 512-575, 10 active): scan2 chunk i-2
// LDS floats: V1s[2][64][116] @0 (cols 100-109 = V2) | z2s[2][64][12] @14848
//             | zst[2][64][100] @16384 ; total 29184 f = 116.7 KB
__global__ __launch_bounds__(576) void fused_scan6(const float* __restrict__ z1p,
                                                   const float* __restrict__ W2,
                                                   float* __restrict__ out) {
    __shared__ float fsm[29184];
    const int tid = threadIdx.x;
    const int b   = blockIdx.x;
    const float dt = FHN_DT;

    float V = 0.f, S = 0.f;

    const int tg = tid - 128;                 // staging/gemm2 threads: 0..383
    int pp = tg >> 6;                         // wave-uniform 0..5
    pp = __builtin_amdgcn_readfirstlane(pp);
    const int r  = tg & 63;
    const int mb = pp * 2;                    // pp<5 handles outputs mb, mb+1
    const int m2 = tid - 512;                 // scan2 lane id 0..9

    // prologue: stage chunk 0 into zst[0]
    if (tid >= 128 && tid < 512) {
        const char* src = (const char*)(z1p + (long)b * 204800);
        char* dst = (char*)&fsm[16384];
#pragma unroll
        for (int j = 0; j < 5; ++j) {
            int idx = j * 384 + tg;
            if (idx < 1600) gl16(src + idx * 16, dst + idx * 16);
        }
        asm volatile("s_waitcnt vmcnt(0)" ::: "memory");
    }
    sync_lds();

    for (int i = 0; i <= 34; ++i) {
        if (tid < 128) {
            // ---- scan1 chunk i: z from LDS ----
            bool a1 = (tid < 100) && (i < 32);
            if (a1) {
                const int cw = i & 1;
                const int zbase = 16384 + cw * 6400 + tid;
                const int vbase = cw * 7424 + tid;
                float zA[16], zB[16];
#pragma unroll
                for (int u = 0; u < 16; ++u) zA[u] = fsm[zbase + u * 100];
#define S1CHUNK(G, ZC, ZN, LOADNEXT) {                                          \
                if (LOADNEXT) {                                                 \
                    _Pragma("unroll")                                           \
                    for (int u = 0; u < 16; ++u)                                \
                        ZN[u] = fsm[zbase + (((G) + 1) * 16 + u) * 100];        \
                }                                                               \
                _Pragma("unroll")                                               \
                for (int u = 0; u < 16; ++u) {                                  \
                    int tl = (G) * 16 + u;                                      \
                    fsm[vbase + tl * 116] = V;                                  \
                    float z  = ZC[u];                                           \
                    float V3 = V * V * V;                                       \
                    float Vn = fmaf(1.f + dt, V,                                \
                                fmaf(-dt / 3.f, V3, fmaf(-dt, S, dt * z)));     \
                    float Sn = fmaf(dt * 0.08f, V + 0.7f - 0.8f * S, S);        \
                    V = Vn; S = Sn;                                             \
                } }
                S1CHUNK(0, zA, zB, 1)
                S1CHUNK(1, zB, zA, 1)
                S1CHUNK(2, zA, zB, 1)
                S1CHUNK(3, zB, zA, 0)
#undef S1CHUNK
            }
        } else if (tid < 512) {
            // ---- (a) DMA-stage z chunk i+1 ----
            if (i <= 30) {
                const char* src = (const char*)(z1p + (long)b * 204800 + (long)(i + 1) * 6400);
                char* dst = (char*)&fsm[16384 + ((i + 1) & 1) * 6400];
#pragma unroll
                for (int j = 0; j < 5; ++j) {
                    int idx = j * 384 + tg;
                    if (idx < 1600) gl16(src + idx * 16, dst + idx * 16);
                }
            }
            // ---- (b) gemm2 chunk i-1 (outputs mb, mb+1) ----
            if (i >= 1 && i <= 32 && pp < 5) {
                const int pb = (i - 1) & 1;
                float acc0 = 0.f, acc1v = 0.f;
                for (int kq = 0; kq < 25; ++kq) {
                    float4 v = *(const float4*)&fsm[pb * 7424 + r * 116 + kq * 4];
                    const float* wp0 = W2 + mb * 100 + kq * 4;        // uniform -> s_load
                    const float* wp1 = W2 + (mb + 1) * 100 + kq * 4;
                    acc0 = fmaf(v.x, wp0[0], acc0);
                    acc0 = fmaf(v.y, wp0[1], acc0);
                    acc0 = fmaf(v.z, wp0[2], acc0);
                    acc0 = fmaf(v.w, wp0[3], acc0);
                    acc1v = fmaf(v.x, wp1[0], acc1v);
                    acc1v = fmaf(v.y, wp1[1], acc1v);
                    acc1v = fmaf(v.z, wp1[2], acc1v);
                    acc1v = fmaf(v.w, wp1[3], acc1v);
                }
                fsm[14848 + pb * 768 + r * 12 + mb]     = 0.5f * acc0;
                fsm[14848 + pb * 768 + r * 12 + mb + 1] = 0.5f * acc1v;
            }
            // ---- (c) copy-out chunk i-3 ----
            if (i >= 3 && pp < 5) {
                const int pbv = (i - 1) & 1;              // == (i-3)&1
                float* dst = out + ((long)b * 2048 + (long)(i - 3) * 64 + r) * 10;
                dst[mb]     = fsm[pbv * 7424 + r * 116 + 100 + mb];
                dst[mb + 1] = fsm[pbv * 7424 + r * 116 + 100 + mb + 1];
            }
            // ---- staging waves drain their DMA (and stores) before barrier ----
            asm volatile("s_waitcnt vmcnt(0)" ::: "memory");
        } else {
            // ---- scan2 chunk i-2 ----
            bool a2 = (m2 < 10) && (i >= 2) && (i < 34);
            if (a2) {
                const int cw = i & 1;                     // == (i-2)&1
#pragma unroll
                for (int sub = 0; sub < 4; ++sub) {
                    float z0s[16];
#pragma unroll
                    for (int u = 0; u < 16; ++u)
                        z0s[u] = fsm[14848 + cw * 768 + (sub * 16 + u) * 12 + m2];
#pragma unroll
                    for (int u = 0; u < 16; ++u) {
                        int tl = sub * 16 + u;
                        fsm[cw * 7424 + tl * 116 + 100 + m2] = V;
                        float z  = z0s[u];
                        float V3 = V * V * V;
                        float Vn = fmaf(1.f + dt, V,
                                    fmaf(-dt / 3.f, V3, fmaf(-dt, S, dt * z)));
                        float Sn = fmaf(dt * 0.08f, V + 0.7f - 0.8f * S, S);
                        V = Vn; S = Sn;
                    }
                }
            }
        }
        sync_lds();
    }
}

extern "C" void kernel_launch(void* const* d_in, const int* in_sizes, int n_in,
                              void* d_out, int out_size, void* d_ws, size_t ws_size,
                              hipStream_t stream) {
    const float* batch = (const float*)d_in[0];   // 64*2048*784
    const float* W1    = (const float*)d_in[1];   // 100*784
    const float* W2    = (const float*)d_in[2];   // 10*100
    float* out = (float*)d_out;                   // 64*2048*10

    char* base = (char*)d_ws;
    unsigned short* Wg = (unsigned short*)base;   // 358400 B
    float* z1p = (float*)(base + 358400);         // 131072*100 f32

    prep_w16<<<700, 256, 0, stream>>>(W1, Wg);
    gemm1_w<<<512, 512, 0, stream>>>(batch, Wg, z1p);
    fused_scan6<<<64, 576, 0, stream>>>(z1p, W2, out);
}